// Round 1
// baseline (2299.742 us; speedup 1.0000x reference)
//
#include <hip/hip_runtime.h>
#include <cstddef>

// Problem constants (fixed by the reference).
#define N_NODES 10000
#define F_DIM   256
#define O2_DIM  256   // 2*O
#define O_DIM   128
#define L_DIM   64
#define E_EDGES 320000

// Output layout (flat, fp32): z | adj | feat | kl
#define Z_OFF    ((size_t)0)
#define ADJ_OFF  ((size_t)N_NODES * L_DIM)                       // 640000
#define FEAT_OFF (ADJ_OFF + (size_t)N_NODES * N_NODES)           // 100640000
#define KL_OFF   (FEAT_OFF + (size_t)N_NODES * F_DIM)            // 103200000

// ---------------------------------------------------------------------------
// Generic 64x64-tile fp32 GEMM: C = A[MxK] @ B[KxN] (+bias) (+relu)
// Requirements: K % 16 == 0, N % 64 == 0. M arbitrary (guarded).
// Block: 256 threads, each computes 4x4 outputs. BK = 16.
// ---------------------------------------------------------------------------
template <bool BIAS, bool RELU>
__global__ __launch_bounds__(256) void gemm64(const float* __restrict__ A,
                                              const float* __restrict__ B,
                                              const float* __restrict__ bias,
                                              float* __restrict__ C,
                                              int M, int Nc, int K) {
  __shared__ float As[16][68];   // k-major, +4 pad keeps 16B row alignment
  __shared__ float Bs[16][64];

  const int tid = threadIdx.x;
  const int tx = tid & 15;       // n direction
  const int ty = tid >> 4;       // m direction
  const int bm0 = blockIdx.y * 64;
  const int bn0 = blockIdx.x * 64;

  float acc[4][4] = {};

  for (int k0 = 0; k0 < K; k0 += 16) {
    // Stage A: 64 rows x 16 k, one float4 per thread, scatter to k-major.
    {
      int row = tid >> 2;
      int kc  = (tid & 3) << 2;
      int gr  = bm0 + row;
      float4 a = make_float4(0.f, 0.f, 0.f, 0.f);
      if (gr < M) a = *(const float4*)(A + (size_t)gr * K + k0 + kc);
      As[kc + 0][row] = a.x;
      As[kc + 1][row] = a.y;
      As[kc + 2][row] = a.z;
      As[kc + 3][row] = a.w;
    }
    // Stage B: 16 k x 64 n, direct float4.
    {
      int kr = tid >> 4;
      int nc = (tid & 15) << 2;
      *(float4*)&Bs[kr][nc] =
          *(const float4*)(B + (size_t)(k0 + kr) * Nc + bn0 + nc);
    }
    __syncthreads();

#pragma unroll
    for (int kk = 0; kk < 16; ++kk) {
      float4 av = *(const float4*)&As[kk][ty << 2];
      float4 bv = *(const float4*)&Bs[kk][tx << 2];
      float am[4] = {av.x, av.y, av.z, av.w};
      float bn[4] = {bv.x, bv.y, bv.z, bv.w};
#pragma unroll
      for (int i = 0; i < 4; ++i)
#pragma unroll
        for (int j = 0; j < 4; ++j)
          acc[i][j] = fmaf(am[i], bn[j], acc[i][j]);
    }
    __syncthreads();
  }

  float4 bb = make_float4(0.f, 0.f, 0.f, 0.f);
  if (BIAS) bb = *(const float4*)(bias + bn0 + (tx << 2));

#pragma unroll
  for (int i = 0; i < 4; ++i) {
    int gr = bm0 + (ty << 2) + i;
    if (gr >= M) continue;
    float4 v;
    v.x = acc[i][0] + bb.x;
    v.y = acc[i][1] + bb.y;
    v.z = acc[i][2] + bb.z;
    v.w = acc[i][3] + bb.w;
    if (RELU) {
      v.x = fmaxf(v.x, 0.f);
      v.y = fmaxf(v.y, 0.f);
      v.z = fmaxf(v.z, 0.f);
      v.w = fmaxf(v.w, 0.f);
    }
    *(float4*)(C + (size_t)gr * Nc + bn0 + (tx << 2)) = v;
  }
}

// ---------------------------------------------------------------------------
// Adjacency GEMM: C = Z @ Z^T,  Z [N_NODES x 64] row-major.
// 128x128 tile, 8x8 per thread, full K=64 staged in LDS (exactly 64 KB).
// VALU-bound by design (8192 FMA-cyc vs ~4.1k LDS-cyc per wave) — staging
// LDS-store bank conflicts are hidden under the FMA stream.
// ---------------------------------------------------------------------------
__global__ __launch_bounds__(256) void adj_gemm(const float* __restrict__ Z,
                                                float* __restrict__ C) {
  __shared__ float As[64][128];  // k-major
  __shared__ float Bs[64][128];

  const int tid = threadIdx.x;
  const int bm0 = blockIdx.y * 128;
  const int bn0 = blockIdx.x * 128;

  // Stage both tiles: 128 rows x 64 k each; 8 float4 per thread per side.
#pragma unroll
  for (int i = 0; i < 8; ++i) {
    int f   = i * 256 + tid;
    int row = f >> 4;            // 0..127
    int kc  = (f & 15) << 2;     // 0..60
    float4 a = make_float4(0.f, 0.f, 0.f, 0.f);
    float4 b = make_float4(0.f, 0.f, 0.f, 0.f);
    int ga = bm0 + row;
    int gb = bn0 + row;
    if (ga < N_NODES) a = *(const float4*)(Z + (size_t)ga * L_DIM + kc);
    if (gb < N_NODES) b = *(const float4*)(Z + (size_t)gb * L_DIM + kc);
    As[kc + 0][row] = a.x; As[kc + 1][row] = a.y;
    As[kc + 2][row] = a.z; As[kc + 3][row] = a.w;
    Bs[kc + 0][row] = b.x; Bs[kc + 1][row] = b.y;
    Bs[kc + 2][row] = b.z; Bs[kc + 3][row] = b.w;
  }
  __syncthreads();

  const int tx = tid & 15;
  const int ty = tid >> 4;
  float acc[8][8] = {};

#pragma unroll 8
  for (int k = 0; k < 64; ++k) {
    float4 a0 = *(const float4*)&As[k][ty << 2];
    float4 a1 = *(const float4*)&As[k][(ty << 2) + 64];
    float4 b0 = *(const float4*)&Bs[k][tx << 2];
    float4 b1 = *(const float4*)&Bs[k][(tx << 2) + 64];
    float am[8] = {a0.x, a0.y, a0.z, a0.w, a1.x, a1.y, a1.z, a1.w};
    float bn[8] = {b0.x, b0.y, b0.z, b0.w, b1.x, b1.y, b1.z, b1.w};
#pragma unroll
    for (int ii = 0; ii < 8; ++ii)
#pragma unroll
      for (int jj = 0; jj < 8; ++jj)
        acc[ii][jj] = fmaf(am[ii], bn[jj], acc[ii][jj]);
  }

#pragma unroll
  for (int ii = 0; ii < 8; ++ii) {
    int gm = bm0 + (ty << 2) + (ii & 3) + ((ii >> 2) << 6);
    if (gm >= N_NODES) continue;
    float* crow = C + (size_t)gm * N_NODES;
#pragma unroll
    for (int jh = 0; jh < 2; ++jh) {
      int gn = bn0 + (tx << 2) + (jh << 6);
      if (gn < N_NODES) {
        float4 v = make_float4(acc[ii][jh * 4 + 0], acc[ii][jh * 4 + 1],
                               acc[ii][jh * 4 + 2], acc[ii][jh * 4 + 3]);
        *(float4*)(crow + gn) = v;
      }
    }
  }
}

// ---------------------------------------------------------------------------
// Edge scatter: agg[dst] += H[src] * ew  (segment_sum via atomics).
// D/4 threads per edge, one float4 gather + 4 atomic adds each.
// ---------------------------------------------------------------------------
template <int D>
__global__ __launch_bounds__(256) void scatter_add(const float* __restrict__ H,
                                                   const int* __restrict__ src,
                                                   const int* __restrict__ dst,
                                                   const float* __restrict__ ew,
                                                   float* __restrict__ agg) {
  constexpr int SH = (D == 256) ? 6 : 5;  // log2(D/4)
  size_t tid = (size_t)blockIdx.x * blockDim.x + threadIdx.x;
  if (tid >= (size_t)E_EDGES << SH) return;
  int e = (int)(tid >> SH);
  int j = (int)(tid & ((1 << SH) - 1)) << 2;
  int s = src[e];
  int d = dst[e];
  float w = ew[e];
  float4 v = *(const float4*)(H + (size_t)s * D + j);
  float* o = agg + (size_t)d * D + j;
  atomicAdd(o + 0, v.x * w);
  atomicAdd(o + 1, v.y * w);
  atomicAdd(o + 2, v.z * w);
  atomicAdd(o + 3, v.w * w);
}

// ---------------------------------------------------------------------------
// In-place bias (+ optional relu): X[i] = act(X[i] + b[i % D])
// ---------------------------------------------------------------------------
template <bool RELU, int D>
__global__ __launch_bounds__(256) void bias_act(float* __restrict__ X,
                                                const float* __restrict__ b,
                                                int total) {
  int i = blockIdx.x * blockDim.x + threadIdx.x;  // float4 index
  if ((i << 2) >= total) return;
  float4 v = ((float4*)X)[i];
  float4 bb = *(const float4*)(b + ((i << 2) % D));
  v.x += bb.x; v.y += bb.y; v.z += bb.z; v.w += bb.w;
  if (RELU) {
    v.x = fmaxf(v.x, 0.f); v.y = fmaxf(v.y, 0.f);
    v.z = fmaxf(v.z, 0.f); v.w = fmaxf(v.w, 0.f);
  }
  ((float4*)X)[i] = v;
}

// ---------------------------------------------------------------------------
// Sampler + KL: z = clip(m,±10) + exp(0.5*clip(v,±10))*eps;
// kl += -0.5 * (1 + log(max(v,1e-7)) - m^2 - max(v,1e-7))
// ---------------------------------------------------------------------------
__global__ __launch_bounds__(256) void sampler(const float* __restrict__ mean,
                                               const float* __restrict__ var,
                                               const float* __restrict__ eps,
                                               float* __restrict__ z,
                                               float* __restrict__ kl) {
  int i = blockIdx.x * blockDim.x + threadIdx.x;
  float kls = 0.f;
  if (i < N_NODES * L_DIM) {
    float m = mean[i];
    float v = var[i];
    float vp = fmaxf(v, 1e-7f);
    kls = 1.0f + logf(vp) - m * m - vp;
    float mc = fminf(fmaxf(m, -10.f), 10.f);
    float vc = fminf(fmaxf(v, -10.f), 10.f);
    z[i] = mc + expf(0.5f * vc) * eps[i];
  }
  // wave reduce (64 lanes) then cross-wave via LDS
#pragma unroll
  for (int off = 32; off > 0; off >>= 1) kls += __shfl_down(kls, off, 64);
  __shared__ float wsum[4];
  if ((threadIdx.x & 63) == 0) wsum[threadIdx.x >> 6] = kls;
  __syncthreads();
  if (threadIdx.x == 0) {
    float s = wsum[0] + wsum[1] + wsum[2] + wsum[3];
    atomicAdd(kl, -0.5f * s);
  }
}

// ---------------------------------------------------------------------------
extern "C" void kernel_launch(void* const* d_in, const int* in_sizes, int n_in,
                              void* d_out, int out_size, void* d_ws,
                              size_t ws_size, hipStream_t stream) {
  const float* x  = (const float*)d_in[0];
  const int*   ei = (const int*)d_in[1];
  const float* ew = (const float*)d_in[2];
  const float* W1 = (const float*)d_in[3];
  const float* b1 = (const float*)d_in[4];
  const float* W2 = (const float*)d_in[5];
  const float* b2 = (const float*)d_in[6];
  const float* Wm = (const float*)d_in[7];
  const float* bm = (const float*)d_in[8];
  const float* Wv = (const float*)d_in[9];
  const float* bv = (const float*)d_in[10];
  const float* Wd = (const float*)d_in[11];
  const float* bd = (const float*)d_in[12];
  const float* eps = (const float*)d_in[13];

  const int* srcv = ei;             // edge_index[0]
  const int* dstv = ei + E_EDGES;   // edge_index[1]

  float* out  = (float*)d_out;
  float* z    = out + Z_OFF;
  float* adj  = out + ADJ_OFF;
  float* feat = out + FEAT_OFF;
  float* kl   = out + KL_OFF;

  // Workspace: two ping-pong buffers of N*256 floats (10.24 MB each).
  float* bufA = (float*)d_ws;
  float* bufB = bufA + (size_t)N_NODES * F_DIM;

  // 1. XW1 = x @ W1  [N, 256] -> bufA
  gemm64<false, false><<<dim3(O2_DIM / 64, (N_NODES + 63) / 64), 256, 0,
                         stream>>>(x, W1, nullptr, bufA, N_NODES, O2_DIM, F_DIM);

  // 2. agg1 = 0 -> bufB
  hipMemsetAsync(bufB, 0, (size_t)N_NODES * O2_DIM * sizeof(float), stream);

  // 3. agg1[dst] += XW1[src] * ew
  {
    size_t tot = (size_t)E_EDGES * (O2_DIM / 4);
    scatter_add<O2_DIM><<<(tot + 255) / 256, 256, 0, stream>>>(bufA, srcv, dstv,
                                                               ew, bufB);
  }

  // 4. h1 = relu(agg1 + b1), in place in bufB
  bias_act<true, O2_DIM><<<((N_NODES * O2_DIM / 4) + 255) / 256, 256, 0,
                           stream>>>(bufB, b1, N_NODES * O2_DIM);

  // 5. H2 = h1 @ W2  [N, 128] -> bufA
  gemm64<false, false><<<dim3(O_DIM / 64, (N_NODES + 63) / 64), 256, 0,
                         stream>>>(bufB, W2, nullptr, bufA, N_NODES, O_DIM,
                                   O2_DIM);

  // 6. agg2 = 0 -> bufB (h1 is dead)
  hipMemsetAsync(bufB, 0, (size_t)N_NODES * O_DIM * sizeof(float), stream);

  // 7. agg2[dst] += H2[src] * ew
  {
    size_t tot = (size_t)E_EDGES * (O_DIM / 4);
    scatter_add<O_DIM><<<(tot + 255) / 256, 256, 0, stream>>>(bufA, srcv, dstv,
                                                              ew, bufB);
  }

  // 8. h2 = agg2 + b2 (no relu), in place in bufB
  bias_act<false, O_DIM><<<((N_NODES * O_DIM / 4) + 255) / 256, 256, 0,
                           stream>>>(bufB, b2, N_NODES * O_DIM);

  // 9. mean = h2@Wm + bm -> bufA[0:N*64]; var = h2@Wv + bv -> bufA[N*64:]
  float* meanb = bufA;
  float* varb  = bufA + (size_t)N_NODES * L_DIM;
  gemm64<true, false><<<dim3(1, (N_NODES + 63) / 64), 256, 0, stream>>>(
      bufB, Wm, bm, meanb, N_NODES, L_DIM, O_DIM);
  gemm64<true, false><<<dim3(1, (N_NODES + 63) / 64), 256, 0, stream>>>(
      bufB, Wv, bv, varb, N_NODES, L_DIM, O_DIM);

  // 10. kl = 0; sampler writes z and accumulates kl
  hipMemsetAsync(kl, 0, sizeof(float), stream);
  sampler<<<(N_NODES * L_DIM + 255) / 256, 256, 0, stream>>>(meanb, varb, eps,
                                                             z, kl);

  // 11. adj = z @ z^T  [N, N]
  adj_gemm<<<dim3((N_NODES + 127) / 128, (N_NODES + 127) / 128), 256, 0,
             stream>>>(z, adj);

  // 12. feat = relu(z @ Wd + bd)  [N, 256]
  gemm64<true, true><<<dim3(F_DIM / 64, (N_NODES + 63) / 64), 256, 0, stream>>>(
      z, Wd, bd, feat, N_NODES, F_DIM, L_DIM);
}

// Round 2
// 794.286 us; speedup vs baseline: 2.8954x; 2.8954x over previous
//
#include <hip/hip_runtime.h>
#include <cstddef>

// Problem constants (fixed by the reference).
#define N_NODES 10000
#define F_DIM   256
#define O2_DIM  256   // 2*O
#define O_DIM   128
#define L_DIM   64
#define E_EDGES 320000

// Output layout (flat, fp32): z | adj | feat | kl
#define Z_OFF    ((size_t)0)
#define ADJ_OFF  ((size_t)N_NODES * L_DIM)                       // 640000
#define FEAT_OFF (ADJ_OFF + (size_t)N_NODES * N_NODES)           // 100640000
#define KL_OFF   (FEAT_OFF + (size_t)N_NODES * F_DIM)            // 103200000

// ---------------------------------------------------------------------------
// Generic 64x64-tile fp32 GEMM: C = A[MxK] @ B[KxN] (+bias) (+relu)
// Requirements: K % 16 == 0, N % 64 == 0. M arbitrary (guarded).
// Block: 256 threads, each computes 4x4 outputs. BK = 16.
// ---------------------------------------------------------------------------
template <bool BIAS, bool RELU>
__global__ __launch_bounds__(256) void gemm64(const float* __restrict__ A,
                                              const float* __restrict__ B,
                                              const float* __restrict__ bias,
                                              float* __restrict__ C,
                                              int M, int Nc, int K) {
  __shared__ float As[16][68];   // k-major, +4 pad keeps 16B row alignment
  __shared__ float Bs[16][64];

  const int tid = threadIdx.x;
  const int tx = tid & 15;       // n direction
  const int ty = tid >> 4;       // m direction
  const int bm0 = blockIdx.y * 64;
  const int bn0 = blockIdx.x * 64;

  float acc[4][4] = {};

  for (int k0 = 0; k0 < K; k0 += 16) {
    // Stage A: 64 rows x 16 k, one float4 per thread, scatter to k-major.
    {
      int row = tid >> 2;
      int kc  = (tid & 3) << 2;
      int gr  = bm0 + row;
      float4 a = make_float4(0.f, 0.f, 0.f, 0.f);
      if (gr < M) a = *(const float4*)(A + (size_t)gr * K + k0 + kc);
      As[kc + 0][row] = a.x;
      As[kc + 1][row] = a.y;
      As[kc + 2][row] = a.z;
      As[kc + 3][row] = a.w;
    }
    // Stage B: 16 k x 64 n, direct float4.
    {
      int kr = tid >> 4;
      int nc = (tid & 15) << 2;
      *(float4*)&Bs[kr][nc] =
          *(const float4*)(B + (size_t)(k0 + kr) * Nc + bn0 + nc);
    }
    __syncthreads();

#pragma unroll
    for (int kk = 0; kk < 16; ++kk) {
      float4 av = *(const float4*)&As[kk][ty << 2];
      float4 bv = *(const float4*)&Bs[kk][tx << 2];
      float am[4] = {av.x, av.y, av.z, av.w};
      float bn[4] = {bv.x, bv.y, bv.z, bv.w};
#pragma unroll
      for (int i = 0; i < 4; ++i)
#pragma unroll
        for (int j = 0; j < 4; ++j)
          acc[i][j] = fmaf(am[i], bn[j], acc[i][j]);
    }
    __syncthreads();
  }

  float4 bb = make_float4(0.f, 0.f, 0.f, 0.f);
  if (BIAS) bb = *(const float4*)(bias + bn0 + (tx << 2));

#pragma unroll
  for (int i = 0; i < 4; ++i) {
    int gr = bm0 + (ty << 2) + i;
    if (gr >= M) continue;
    float4 v;
    v.x = acc[i][0] + bb.x;
    v.y = acc[i][1] + bb.y;
    v.z = acc[i][2] + bb.z;
    v.w = acc[i][3] + bb.w;
    if (RELU) {
      v.x = fmaxf(v.x, 0.f);
      v.y = fmaxf(v.y, 0.f);
      v.z = fmaxf(v.z, 0.f);
      v.w = fmaxf(v.w, 0.f);
    }
    *(float4*)(C + (size_t)gr * Nc + bn0 + (tx << 2)) = v;
  }
}

// ---------------------------------------------------------------------------
// Adjacency GEMM: C = Z @ Z^T,  Z [N_NODES x 64] row-major.
// 128x128 tile, 8x8 per thread, full K=64 staged in LDS (exactly 64 KB).
// ---------------------------------------------------------------------------
__global__ __launch_bounds__(256) void adj_gemm(const float* __restrict__ Z,
                                                float* __restrict__ C) {
  __shared__ float As[64][128];  // k-major
  __shared__ float Bs[64][128];

  const int tid = threadIdx.x;
  const int bm0 = blockIdx.y * 128;
  const int bn0 = blockIdx.x * 128;

#pragma unroll
  for (int i = 0; i < 8; ++i) {
    int f   = i * 256 + tid;
    int row = f >> 4;            // 0..127
    int kc  = (f & 15) << 2;     // 0..60
    float4 a = make_float4(0.f, 0.f, 0.f, 0.f);
    float4 b = make_float4(0.f, 0.f, 0.f, 0.f);
    int ga = bm0 + row;
    int gb = bn0 + row;
    if (ga < N_NODES) a = *(const float4*)(Z + (size_t)ga * L_DIM + kc);
    if (gb < N_NODES) b = *(const float4*)(Z + (size_t)gb * L_DIM + kc);
    As[kc + 0][row] = a.x; As[kc + 1][row] = a.y;
    As[kc + 2][row] = a.z; As[kc + 3][row] = a.w;
    Bs[kc + 0][row] = b.x; Bs[kc + 1][row] = b.y;
    Bs[kc + 2][row] = b.z; Bs[kc + 3][row] = b.w;
  }
  __syncthreads();

  const int tx = tid & 15;
  const int ty = tid >> 4;
  float acc[8][8] = {};

#pragma unroll 8
  for (int k = 0; k < 64; ++k) {
    float4 a0 = *(const float4*)&As[k][ty << 2];
    float4 a1 = *(const float4*)&As[k][(ty << 2) + 64];
    float4 b0 = *(const float4*)&Bs[k][tx << 2];
    float4 b1 = *(const float4*)&Bs[k][(tx << 2) + 64];
    float am[8] = {a0.x, a0.y, a0.z, a0.w, a1.x, a1.y, a1.z, a1.w};
    float bn[8] = {b0.x, b0.y, b0.z, b0.w, b1.x, b1.y, b1.z, b1.w};
#pragma unroll
    for (int ii = 0; ii < 8; ++ii)
#pragma unroll
      for (int jj = 0; jj < 8; ++jj)
        acc[ii][jj] = fmaf(am[ii], bn[jj], acc[ii][jj]);
  }

#pragma unroll
  for (int ii = 0; ii < 8; ++ii) {
    int gm = bm0 + (ty << 2) + (ii & 3) + ((ii >> 2) << 6);
    if (gm >= N_NODES) continue;
    float* crow = C + (size_t)gm * N_NODES;
#pragma unroll
    for (int jh = 0; jh < 2; ++jh) {
      int gn = bn0 + (tx << 2) + (jh << 6);
      if (gn < N_NODES) {
        float4 v = make_float4(acc[ii][jh * 4 + 0], acc[ii][jh * 4 + 1],
                               acc[ii][jh * 4 + 2], acc[ii][jh * 4 + 3]);
        *(float4*)(crow + gn) = v;
      }
    }
  }
}

// ---------------------------------------------------------------------------
// CSR build: histogram of dst, exclusive scan, cursor-based fill.
// CSR arrays live in the adj output region (written long before adj_gemm).
// ---------------------------------------------------------------------------
__global__ __launch_bounds__(256) void hist_kernel(const int* __restrict__ dst,
                                                   int* __restrict__ deg) {
  int e = blockIdx.x * blockDim.x + threadIdx.x;
  if (e < E_EDGES) atomicAdd(&deg[dst[e]], 1);
}

// Single-block exclusive scan over N_NODES degree counts.
// Writes row_start[0..N] and cursor[0..N-1] (= row_start copy).
__global__ __launch_bounds__(256) void scan_kernel(const int* __restrict__ deg,
                                                   int* __restrict__ row_start,
                                                   int* __restrict__ cursor) {
  constexpr int CH = (N_NODES + 255) / 256;  // 40
  const int t = threadIdx.x;
  __shared__ int ps[256];

  int base = t * CH;
  int sum = 0;
  for (int i = base; i < base + CH && i < N_NODES; ++i) sum += deg[i];
  ps[t] = sum;
  __syncthreads();
  // inclusive Hillis-Steele scan
  for (int off = 1; off < 256; off <<= 1) {
    int v = (t >= off) ? ps[t - off] : 0;
    __syncthreads();
    ps[t] += v;
    __syncthreads();
  }
  int running = ps[t] - sum;  // exclusive base for this chunk
  for (int i = base; i < base + CH && i < N_NODES; ++i) {
    row_start[i] = running;
    cursor[i] = running;
    running += deg[i];
  }
  if (t == 255) row_start[N_NODES] = ps[255];
}

__global__ __launch_bounds__(256) void fill_kernel(
    const int* __restrict__ src, const int* __restrict__ dst,
    const float* __restrict__ ew, int* __restrict__ cursor,
    int* __restrict__ csr_src, float* __restrict__ csr_w) {
  int e = blockIdx.x * blockDim.x + threadIdx.x;
  if (e >= E_EDGES) return;
  int d = dst[e];
  int pos = atomicAdd(&cursor[d], 1);
  csr_src[pos] = src[e];
  csr_w[pos] = ew[e];
}

// ---------------------------------------------------------------------------
// Gather-based GCN aggregation: out[n] = act( sum_{e: dst=n} w_e * H[src_e] + b )
// One wave per node; lane holds VEC = D/64 features in registers.
// Edge loop unrolled x4 so the 4 row loads issue concurrently.
// ---------------------------------------------------------------------------
template <int D, bool RELU>
__global__ __launch_bounds__(256) void gcn_gather(
    const float* __restrict__ H, const int* __restrict__ row_start,
    const int* __restrict__ csr_src, const float* __restrict__ csr_w,
    const float* __restrict__ bias, float* __restrict__ out) {
  constexpr int VEC = D / 64;  // 4 (D=256) or 2 (D=128)
  const int wid = threadIdx.x >> 6;
  const int lane = threadIdx.x & 63;
  const int n = blockIdx.x * 4 + wid;
  if (n >= N_NODES) return;

  const int beg = row_start[n];
  const int end = row_start[n + 1];

  float acc[VEC] = {};
  int i = beg;
  for (; i + 4 <= end; i += 4) {
    int ss[4];
    float ww[4];
#pragma unroll
    for (int u = 0; u < 4; ++u) {
      ss[u] = csr_src[i + u];
      ww[u] = csr_w[i + u];
    }
    float vv[4][VEC];
#pragma unroll
    for (int u = 0; u < 4; ++u) {
      const float* rp = H + (size_t)ss[u] * D + lane * VEC;
      if constexpr (VEC == 4) {
        float4 v = *(const float4*)rp;
        vv[u][0] = v.x; vv[u][1] = v.y; vv[u][2] = v.z; vv[u][3] = v.w;
      } else {
        float2 v = *(const float2*)rp;
        vv[u][0] = v.x; vv[u][1] = v.y;
      }
    }
#pragma unroll
    for (int u = 0; u < 4; ++u)
#pragma unroll
      for (int c = 0; c < VEC; ++c) acc[c] = fmaf(vv[u][c], ww[u], acc[c]);
  }
  for (; i < end; ++i) {
    int s = csr_src[i];
    float w = csr_w[i];
    const float* rp = H + (size_t)s * D + lane * VEC;
    if constexpr (VEC == 4) {
      float4 v = *(const float4*)rp;
      acc[0] = fmaf(v.x, w, acc[0]);
      acc[1] = fmaf(v.y, w, acc[1]);
      acc[2] = fmaf(v.z, w, acc[2]);
      acc[3] = fmaf(v.w, w, acc[3]);
    } else {
      float2 v = *(const float2*)rp;
      acc[0] = fmaf(v.x, w, acc[0]);
      acc[1] = fmaf(v.y, w, acc[1]);
    }
  }

  float* op = out + (size_t)n * D + lane * VEC;
  if constexpr (VEC == 4) {
    float4 b = *(const float4*)(bias + lane * 4);
    float4 r = make_float4(acc[0] + b.x, acc[1] + b.y, acc[2] + b.z,
                           acc[3] + b.w);
    if (RELU) {
      r.x = fmaxf(r.x, 0.f); r.y = fmaxf(r.y, 0.f);
      r.z = fmaxf(r.z, 0.f); r.w = fmaxf(r.w, 0.f);
    }
    *(float4*)op = r;
  } else {
    float2 b = *(const float2*)(bias + lane * 2);
    float2 r = make_float2(acc[0] + b.x, acc[1] + b.y);
    if (RELU) {
      r.x = fmaxf(r.x, 0.f); r.y = fmaxf(r.y, 0.f);
    }
    *(float2*)op = r;
  }
}

// ---------------------------------------------------------------------------
// Sampler + KL: z = clip(m,±10) + exp(0.5*clip(v,±10))*eps;
// kl += -0.5 * (1 + log(max(v,1e-7)) - m^2 - max(v,1e-7))
// ---------------------------------------------------------------------------
__global__ __launch_bounds__(256) void sampler(const float* __restrict__ mean,
                                               const float* __restrict__ var,
                                               const float* __restrict__ eps,
                                               float* __restrict__ z,
                                               float* __restrict__ kl) {
  int i = blockIdx.x * blockDim.x + threadIdx.x;
  float kls = 0.f;
  if (i < N_NODES * L_DIM) {
    float m = mean[i];
    float v = var[i];
    float vp = fmaxf(v, 1e-7f);
    kls = 1.0f + logf(vp) - m * m - vp;
    float mc = fminf(fmaxf(m, -10.f), 10.f);
    float vc = fminf(fmaxf(v, -10.f), 10.f);
    z[i] = mc + expf(0.5f * vc) * eps[i];
  }
#pragma unroll
  for (int off = 32; off > 0; off >>= 1) kls += __shfl_down(kls, off, 64);
  __shared__ float wsum[4];
  if ((threadIdx.x & 63) == 0) wsum[threadIdx.x >> 6] = kls;
  __syncthreads();
  if (threadIdx.x == 0) {
    float s = wsum[0] + wsum[1] + wsum[2] + wsum[3];
    atomicAdd(kl, -0.5f * s);
  }
}

// ---------------------------------------------------------------------------
extern "C" void kernel_launch(void* const* d_in, const int* in_sizes, int n_in,
                              void* d_out, int out_size, void* d_ws,
                              size_t ws_size, hipStream_t stream) {
  const float* x  = (const float*)d_in[0];
  const int*   ei = (const int*)d_in[1];
  const float* ew = (const float*)d_in[2];
  const float* W1 = (const float*)d_in[3];
  const float* b1 = (const float*)d_in[4];
  const float* W2 = (const float*)d_in[5];
  const float* b2 = (const float*)d_in[6];
  const float* Wm = (const float*)d_in[7];
  const float* bm = (const float*)d_in[8];
  const float* Wv = (const float*)d_in[9];
  const float* bv = (const float*)d_in[10];
  const float* Wd = (const float*)d_in[11];
  const float* bd = (const float*)d_in[12];
  const float* eps = (const float*)d_in[13];

  const int* srcv = ei;             // edge_index[0]
  const int* dstv = ei + E_EDGES;   // edge_index[1]

  float* out  = (float*)d_out;
  float* z    = out + Z_OFF;
  float* adj  = out + ADJ_OFF;
  float* feat = out + FEAT_OFF;
  float* kl   = out + KL_OFF;

  // Workspace: two ping-pong buffers of N*256 floats (10.24 MB each).
  float* bufA = (float*)d_ws;
  float* bufB = bufA + (size_t)N_NODES * F_DIM;

  // CSR scratch lives in the adj output region (adj is written last).
  int* deg       = (int*)adj;
  int* row_start = deg + N_NODES;          // N+1 entries
  int* cursor    = row_start + N_NODES + 1;
  int* csr_src   = cursor + N_NODES;
  float* csr_w   = (float*)(csr_src + E_EDGES);

  // --- CSR build (once, reused by both convs) ---
  hipMemsetAsync(deg, 0, N_NODES * sizeof(int), stream);
  hist_kernel<<<(E_EDGES + 255) / 256, 256, 0, stream>>>(dstv, deg);
  scan_kernel<<<1, 256, 0, stream>>>(deg, row_start, cursor);
  fill_kernel<<<(E_EDGES + 255) / 256, 256, 0, stream>>>(srcv, dstv, ew, cursor,
                                                         csr_src, csr_w);

  // 1. XW1 = x @ W1  [N, 256] -> bufA
  gemm64<false, false><<<dim3(O2_DIM / 64, (N_NODES + 63) / 64), 256, 0,
                         stream>>>(x, W1, nullptr, bufA, N_NODES, O2_DIM, F_DIM);

  // 2. h1 = relu(A_hat @ XW1 + b1) -> bufB (gather, fused bias+relu)
  gcn_gather<O2_DIM, true><<<(N_NODES + 3) / 4, 256, 0, stream>>>(
      bufA, row_start, csr_src, csr_w, b1, bufB);

  // 3. H2 = h1 @ W2  [N, 128] -> bufA
  gemm64<false, false><<<dim3(O_DIM / 64, (N_NODES + 63) / 64), 256, 0,
                         stream>>>(bufB, W2, nullptr, bufA, N_NODES, O_DIM,
                                   O2_DIM);

  // 4. h2 = A_hat @ H2 + b2 -> bufB (gather, fused bias)
  gcn_gather<O_DIM, false><<<(N_NODES + 3) / 4, 256, 0, stream>>>(
      bufA, row_start, csr_src, csr_w, b2, bufB);

  // 5. mean = h2@Wm + bm; var = h2@Wv + bv -> bufA
  float* meanb = bufA;
  float* varb  = bufA + (size_t)N_NODES * L_DIM;
  gemm64<true, false><<<dim3(1, (N_NODES + 63) / 64), 256, 0, stream>>>(
      bufB, Wm, bm, meanb, N_NODES, L_DIM, O_DIM);
  gemm64<true, false><<<dim3(1, (N_NODES + 63) / 64), 256, 0, stream>>>(
      bufB, Wv, bv, varb, N_NODES, L_DIM, O_DIM);

  // 6. kl = 0; sampler writes z and accumulates kl
  hipMemsetAsync(kl, 0, sizeof(float), stream);
  sampler<<<(N_NODES * L_DIM + 255) / 256, 256, 0, stream>>>(meanb, varb, eps,
                                                             z, kl);

  // 7. adj = z @ z^T  [N, N]  (overwrites the CSR scratch — CSR is dead)
  adj_gemm<<<dim3((N_NODES + 127) / 128, (N_NODES + 127) / 128), 256, 0,
             stream>>>(z, adj);

  // 8. feat = relu(z @ Wd + bd)  [N, 256]
  gemm64<true, true><<<dim3(F_DIM / 64, (N_NODES + 63) / 64), 256, 0, stream>>>(
      z, Wd, bd, feat, N_NODES, F_DIM, L_DIM);
}